// Round 6
// baseline (374.542 us; speedup 1.0000x reference)
//
#include <hip/hip_runtime.h>

// MSDeformAttn — R6: single fused mega-kernel (gemm1+softmax+sampler+gemm2 in
// LDS) + one convert kernel. ws shrunk 112 MB -> 22.6 MB: cross-round evidence
// shows timed harness overhead scales ~2 us/MB of ws (poison restore), which
// was ~180 us of R5's 338. Lean R5 sampler design retained (f16 packed lerp,
// clamp+mask weights, ~50 VGPR).
// B=2, C=256, nH=8, nL=4, nP=4, hd=32, Len=21760.
// Shapes compile-time: [[128,128],[64,64],[32,32],[16,16]], starts [0,16384,20480,21504].

#define NH 8
#define NL 4
#define NP 4
#define CDIM 256
#define HD 32
#define QB 16
#define QSTR 264   // padded row stride: shorts for qp/pre, floats for offs
#define ASTR 132   // padded row stride for aw (floats)

typedef short bf16x8 __attribute__((ext_vector_type(8)));
typedef float f32x4  __attribute__((ext_vector_type(4)));
typedef _Float16 f16x8v __attribute__((ext_vector_type(8)));
typedef _Float16 f16x4v __attribute__((ext_vector_type(4)));

#define SPLAT8(x) (f16x8v){(x),(x),(x),(x),(x),(x),(x),(x)}

__device__ __forceinline__ short f2bf(float x) {
    union { float f; unsigned u; } v; v.f = x;
    const unsigned r = v.u + 0x7FFFu + ((v.u >> 16) & 1u);
    return (short)(r >> 16);
}

__constant__ int LVL_S_C[4] = {0, 16384, 20480, 21504};

// ---- convert: weights (blocks [0,640)) + features f16 (blocks [640,...)) ----
__global__ __launch_bounds__(256) void convert_all(
    const float* __restrict__ W_off, const float* __restrict__ W_attn,
    const float* __restrict__ W_out, const float* __restrict__ feat,
    short* __restrict__ wt, _Float16* __restrict__ fh, int n4)
{
    const int bid = blockIdx.x;
    if (bid < 640) {
        const int gid = bid * 256 + threadIdx.x;
        if (gid < 65536) {
            const int c = gid >> 8, k = gid & 255;
            wt[gid] = f2bf(W_off[k * 256 + c]);
        } else if (gid < 98304) {
            const int g = gid - 65536, c = g >> 8, k = g & 255;
            wt[gid] = f2bf(W_attn[k * 128 + c]);
        } else if (gid < 163840) {
            const int g = gid - 98304, c = g >> 8, k = g & 255;
            wt[gid] = f2bf(W_out[k * 256 + c]);
        }
    } else {
        const int gid = (bid - 640) * 256 + threadIdx.x;
        if (gid < n4) {
            const float4 v = *(const float4*)&feat[gid * 4];
            f16x4v o;
            o[0] = (_Float16)v.x; o[1] = (_Float16)v.y;
            o[2] = (_Float16)v.z; o[3] = (_Float16)v.w;
            *(f16x4v*)&fh[gid * 4] = o;
        }
    }
}

// ---- mega: per 16-row block: gemm1 (MFMA) -> softmax -> sample -> gemm2 ----
__global__ __launch_bounds__(256) void msda_mega(
    const float* __restrict__ query, const float* __restrict__ ref_pts,
    const _Float16* __restrict__ feath, const short* __restrict__ wt,
    const float* __restrict__ b_off, const float* __restrict__ b_attn,
    const float* __restrict__ b_out, float* __restrict__ out, int Len)
{
    const int t = threadIdx.x;
    const int lane = t & 63;
    const int wave = t >> 6;
    const int qr = lane & 15;
    const int quad = lane >> 4;
    const long long qbase = (long long)blockIdx.x * QB;
    const int b = (int)(qbase / Len);   // Len % QB == 0, no crossing

    // union: qp (bf16 [16][QSTR], 8448 B) then offs (f32 [16][QSTR], 16896 B)
    __shared__ __align__(16) char uni[QB * QSTR * 4];
    short* qp = (short*)uni;
    float* offs_lds = (float*)uni;                 // permuted: [i][rem*8+h], rem=(l*4+p)*2+xy
    __shared__ float aw_lds[QB * ASTR];            // permuted: [i][rem*8+h], rem=l*4+p
    __shared__ __align__(16) short pre_lds[QB * QSTR];  // natural: [i][c]
    __shared__ float ref_sm[QB][2];

    // ---- stage query natural [i][k] (fp32 -> bf16) + ref ----
    #pragma unroll
    for (int it = 0; it < 4; ++it) {
        const int e = it * 1024 + t * 4;
        const int i = e >> 8, k = e & 255;
        const float4 v = *(const float4*)&query[(qbase + i) * CDIM + k];
        short4 o;
        o.x = f2bf(v.x); o.y = f2bf(v.y); o.z = f2bf(v.z); o.w = f2bf(v.w);
        *(short4*)&qp[i * QSTR + k] = o;
    }
    if (t < QB * 2) ref_sm[t >> 1][t & 1] = ref_pts[(qbase + (t >> 1)) * 2 + (t & 1)];
    __syncthreads();

    const short* __restrict__ Wt_off  = wt;
    const short* __restrict__ Wt_attn = wt + 65536;
    const short* __restrict__ Wt_out  = wt + 98304;

    // ---- GEMM1: offs (N=256) + attn logits (N=128) ----
    {
        f32x4 acc[4], acca[2];
        #pragma unroll
        for (int j = 0; j < 4; ++j) acc[j] = (f32x4){0.f, 0.f, 0.f, 0.f};
        #pragma unroll
        for (int j = 0; j < 2; ++j) acca[j] = (f32x4){0.f, 0.f, 0.f, 0.f};

        const short* bb_off  = Wt_off  + qr * 256 + quad * 8;
        const short* bb_attn = Wt_attn + qr * 256 + quad * 8;
        #pragma unroll
        for (int s = 0; s < 8; ++s) {
            const bf16x8 af = *(const bf16x8*)&qp[qr * QSTR + s * 32 + quad * 8];
            #pragma unroll
            for (int j = 0; j < 4; ++j) {
                const bf16x8 bf = *(const bf16x8*)(bb_off + ((j * 4 + wave) * 16) * 256 + s * 32);
                acc[j] = __builtin_amdgcn_mfma_f32_16x16x32_bf16(af, bf, acc[j], 0, 0, 0);
            }
            #pragma unroll
            for (int j = 0; j < 2; ++j) {
                const bf16x8 bf = *(const bf16x8*)(bb_attn + ((j * 4 + wave) * 16) * 256 + s * 32);
                acca[j] = __builtin_amdgcn_mfma_f32_16x16x32_bf16(af, bf, acca[j], 0, 0, 0);
            }
        }
        __syncthreads();   // all qp reads done; union becomes offs_lds

        // D layout: col = qr, row = quad*4 + r. Permuted head-major stores.
        #pragma unroll
        for (int j = 0; j < 4; ++j) {
            const int col = (j * 4 + wave) * 16 + qr;
            const float bo = b_off[col];
            const int h = col >> 5, rem = col & 31;
            #pragma unroll
            for (int r = 0; r < 4; ++r)
                offs_lds[(quad * 4 + r) * QSTR + rem * 8 + h] = acc[j][r] + bo;
        }
        #pragma unroll
        for (int j = 0; j < 2; ++j) {
            const int col = (j * 4 + wave) * 16 + qr;
            const float ba = b_attn[col];
            const int h = col >> 4, rem = col & 15;
            #pragma unroll
            for (int r = 0; r < 4; ++r)
                aw_lds[(quad * 4 + r) * ASTR + rem * 8 + h] = acca[j][r] + ba;
        }
    }
    __syncthreads();

    // ---- softmax per (row, head), 128 threads ----
    if (t < QB * NH) {
        const int i = t >> 3, h = t & 7;
        float* row = &aw_lds[i * ASTR];
        float vals[16], mx = -1e30f;
        #pragma unroll
        for (int j = 0; j < 16; ++j) { vals[j] = row[j * 8 + h]; mx = fmaxf(mx, vals[j]); }
        float s = 0.f;
        #pragma unroll
        for (int j = 0; j < 16; ++j) { vals[j] = __expf(vals[j] - mx); s += vals[j]; }
        const float inv = 1.f / s;
        #pragma unroll
        for (int j = 0; j < 16; ++j) row[j * 8 + h] = vals[j] * inv;
    }
    __syncthreads();

    // ---- sampling: 2 passes x 8 rows; 32 lanes/row: h = l32>>2, ct = l32&3 ----
    {
        const int rl = t >> 5;
        const int l32 = t & 31;
        const int h = l32 >> 2, ct = l32 & 3;
        const int c0 = h * HD + ct * 8;
        #pragma unroll 1
        for (int pass = 0; pass < 2; ++pass) {
            const int i = pass * 8 + rl;
            const float rx = ref_sm[i][0], ry = ref_sm[i][1];
            const float* __restrict__ offr = &offs_lds[i * QSTR];
            const float* __restrict__ awr  = &aw_lds[i * ASTR];
            float acc[8];
            #pragma unroll
            for (int c = 0; c < 8; ++c) acc[c] = 0.f;
            #pragma unroll
            for (int l = 0; l < NL; ++l) {
                const int Wl = 128 >> l;
                const int base = (b * Len + LVL_S_C[l]) * CDIM + c0;
                #pragma unroll
                for (int p = 0; p < NP; ++p) {
                    const int pi = l * 4 + p;
                    const float ox = offr[pi * 16 + h];
                    const float oy = offr[pi * 16 + 8 + h];
                    const float a  = awr[pi * 8 + h];
                    const float x = fmaf(rx, (float)Wl, ox) - 0.5f;
                    const float y = fmaf(ry, (float)Wl, oy) - 0.5f;
                    const float xf = floorf(x), yf = floorf(y);
                    const int x0 = (int)xf, y0 = (int)yf;
                    const float wx = x - xf, wy = y - yf;
                    const float ax0 = ((unsigned)x0     < (unsigned)Wl) ? (1.f - wx) : 0.f;
                    const float ax1 = ((unsigned)(x0+1) < (unsigned)Wl) ? wx         : 0.f;
                    const float ay0 = (((unsigned)y0     < (unsigned)Wl) ? (1.f - wy) : 0.f) * a;
                    const float ay1 = (((unsigned)(y0+1) < (unsigned)Wl) ? wy         : 0.f) * a;
                    const int x0c = min(max(x0, 0), Wl - 1), x1c = min(max(x0 + 1, 0), Wl - 1);
                    const int y0c = min(max(y0, 0), Wl - 1), y1c = min(max(y0 + 1, 0), Wl - 1);
                    const int r00 = base + (y0c * Wl + x0c) * CDIM;
                    const int r01 = base + (y0c * Wl + x1c) * CDIM;
                    const int r10 = base + (y1c * Wl + x0c) * CDIM;
                    const int r11 = base + (y1c * Wl + x1c) * CDIM;
                    const f16x8v v00 = *(const f16x8v*)(feath + r00);
                    const f16x8v v01 = *(const f16x8v*)(feath + r01);
                    const f16x8v v10 = *(const f16x8v*)(feath + r10);
                    const f16x8v v11 = *(const f16x8v*)(feath + r11);
                    const f16x8v W00 = SPLAT8((_Float16)(ax0 * ay0));
                    const f16x8v W01 = SPLAT8((_Float16)(ax1 * ay0));
                    const f16x8v W10 = SPLAT8((_Float16)(ax0 * ay1));
                    const f16x8v W11 = SPLAT8((_Float16)(ax1 * ay1));
                    const f16x8v bil = v00 * W00 + v01 * W01 + v10 * W10 + v11 * W11;
                    #pragma unroll
                    for (int c = 0; c < 8; ++c) acc[c] += (float)bil[c];
                }
            }
            bf16x8 pv;
            #pragma unroll
            for (int c = 0; c < 8; ++c) pv[c] = f2bf(acc[c]);
            *(bf16x8*)&pre_lds[i * QSTR + c0] = pv;   // natural layout, contiguous b128
        }
    }
    __syncthreads();

    // ---- GEMM2: out = pre @ W_out + b_out ----
    {
        f32x4 acc[4];
        #pragma unroll
        for (int j = 0; j < 4; ++j) acc[j] = (f32x4){0.f, 0.f, 0.f, 0.f};
        const short* bb = Wt_out + qr * 256 + quad * 8;
        #pragma unroll
        for (int s = 0; s < 8; ++s) {
            const bf16x8 af = *(const bf16x8*)&pre_lds[qr * QSTR + s * 32 + quad * 8];
            #pragma unroll
            for (int j = 0; j < 4; ++j) {
                const bf16x8 bf = *(const bf16x8*)(bb + ((j * 4 + wave) * 16) * 256 + s * 32);
                acc[j] = __builtin_amdgcn_mfma_f32_16x16x32_bf16(af, bf, acc[j], 0, 0, 0);
            }
        }
        #pragma unroll
        for (int j = 0; j < 4; ++j) {
            const int col = (j * 4 + wave) * 16 + qr;
            const float bo = b_out[col];
            #pragma unroll
            for (int r = 0; r < 4; ++r)
                out[(qbase + quad * 4 + r) * CDIM + col] = acc[j][r] + bo;
        }
    }
}

// ---- fallback: fused kernel, fp32 features (ws < 22.6 MB) ----
__global__ __launch_bounds__(256) void msda_fused_fb(
    const float* __restrict__ query, const float* __restrict__ ref_pts,
    const float* __restrict__ feat_f32, const short* __restrict__ wt,
    const float* __restrict__ b_off, const float* __restrict__ b_attn,
    const float* __restrict__ b_out, float* __restrict__ out, int Len)
{
    const int t = threadIdx.x;
    const int lane = t & 63;
    const int wave = t >> 6;
    const int qr = lane & 15;
    const int quad = lane >> 4;
    const long long qbase = (long long)blockIdx.x * QB;
    const int b = (int)(qbase / Len);

    __shared__ __align__(16) char uni[QB * QSTR * 4];
    short* qp = (short*)uni;
    float* offs_lds = (float*)uni;
    __shared__ float aw_lds[QB * ASTR];
    __shared__ __align__(16) short pre_lds[QB * QSTR];
    __shared__ float ref_sm[QB][2];

    #pragma unroll
    for (int it = 0; it < 4; ++it) {
        const int e = it * 1024 + t * 4;
        const int i = e >> 8, k = e & 255;
        const float4 v = *(const float4*)&query[(qbase + i) * CDIM + k];
        short4 o;
        o.x = f2bf(v.x); o.y = f2bf(v.y); o.z = f2bf(v.z); o.w = f2bf(v.w);
        *(short4*)&qp[i * QSTR + k] = o;
    }
    if (t < QB * 2) ref_sm[t >> 1][t & 1] = ref_pts[(qbase + (t >> 1)) * 2 + (t & 1)];
    __syncthreads();

    const short* __restrict__ Wt_off  = wt;
    const short* __restrict__ Wt_attn = wt + 65536;
    const short* __restrict__ Wt_out  = wt + 98304;

    {
        f32x4 acc[4], acca[2];
        #pragma unroll
        for (int j = 0; j < 4; ++j) acc[j] = (f32x4){0.f, 0.f, 0.f, 0.f};
        #pragma unroll
        for (int j = 0; j < 2; ++j) acca[j] = (f32x4){0.f, 0.f, 0.f, 0.f};
        const short* bb_off  = Wt_off  + qr * 256 + quad * 8;
        const short* bb_attn = Wt_attn + qr * 256 + quad * 8;
        #pragma unroll
        for (int s = 0; s < 8; ++s) {
            const bf16x8 af = *(const bf16x8*)&qp[qr * QSTR + s * 32 + quad * 8];
            #pragma unroll
            for (int j = 0; j < 4; ++j) {
                const bf16x8 bf = *(const bf16x8*)(bb_off + ((j * 4 + wave) * 16) * 256 + s * 32);
                acc[j] = __builtin_amdgcn_mfma_f32_16x16x32_bf16(af, bf, acc[j], 0, 0, 0);
            }
            #pragma unroll
            for (int j = 0; j < 2; ++j) {
                const bf16x8 bf = *(const bf16x8*)(bb_attn + ((j * 4 + wave) * 16) * 256 + s * 32);
                acca[j] = __builtin_amdgcn_mfma_f32_16x16x32_bf16(af, bf, acca[j], 0, 0, 0);
            }
        }
        __syncthreads();
        #pragma unroll
        for (int j = 0; j < 4; ++j) {
            const int col = (j * 4 + wave) * 16 + qr;
            const float bo = b_off[col];
            const int h = col >> 5, rem = col & 31;
            #pragma unroll
            for (int r = 0; r < 4; ++r)
                offs_lds[(quad * 4 + r) * QSTR + rem * 8 + h] = acc[j][r] + bo;
        }
        #pragma unroll
        for (int j = 0; j < 2; ++j) {
            const int col = (j * 4 + wave) * 16 + qr;
            const float ba = b_attn[col];
            const int h = col >> 4, rem = col & 15;
            #pragma unroll
            for (int r = 0; r < 4; ++r)
                aw_lds[(quad * 4 + r) * ASTR + rem * 8 + h] = acca[j][r] + ba;
        }
    }
    __syncthreads();

    if (t < QB * NH) {
        const int i = t >> 3, h = t & 7;
        float* row = &aw_lds[i * ASTR];
        float vals[16], mx = -1e30f;
        #pragma unroll
        for (int j = 0; j < 16; ++j) { vals[j] = row[j * 8 + h]; mx = fmaxf(mx, vals[j]); }
        float s = 0.f;
        #pragma unroll
        for (int j = 0; j < 16; ++j) { vals[j] = __expf(vals[j] - mx); s += vals[j]; }
        const float inv = 1.f / s;
        #pragma unroll
        for (int j = 0; j < 16; ++j) row[j * 8 + h] = vals[j] * inv;
    }
    __syncthreads();

    {
        const int rl = t >> 5;
        const int l32 = t & 31;
        const int h = l32 >> 2, ct = l32 & 3;
        const int c0 = h * HD + ct * 8;
        #pragma unroll 1
        for (int pass = 0; pass < 2; ++pass) {
            const int i = pass * 8 + rl;
            const float rx = ref_sm[i][0], ry = ref_sm[i][1];
            const float* __restrict__ offr = &offs_lds[i * QSTR];
            const float* __restrict__ awr  = &aw_lds[i * ASTR];
            float acc[8];
            #pragma unroll
            for (int c = 0; c < 8; ++c) acc[c] = 0.f;
            #pragma unroll
            for (int l = 0; l < NL; ++l) {
                const int Wl = 128 >> l;
                const int base = (b * Len + LVL_S_C[l]) * CDIM + c0;
                #pragma unroll 2
                for (int p = 0; p < NP; ++p) {
                    const int pi = l * 4 + p;
                    const float ox = offr[pi * 16 + h];
                    const float oy = offr[pi * 16 + 8 + h];
                    const float a  = awr[pi * 8 + h];
                    const float x = fmaf(rx, (float)Wl, ox) - 0.5f;
                    const float y = fmaf(ry, (float)Wl, oy) - 0.5f;
                    const float xf = floorf(x), yf = floorf(y);
                    const int x0 = (int)xf, y0 = (int)yf;
                    const float wx = x - xf, wy = y - yf;
                    const float ax0 = ((unsigned)x0     < (unsigned)Wl) ? (1.f - wx) : 0.f;
                    const float ax1 = ((unsigned)(x0+1) < (unsigned)Wl) ? wx         : 0.f;
                    const float ay0 = (((unsigned)y0     < (unsigned)Wl) ? (1.f - wy) : 0.f) * a;
                    const float ay1 = (((unsigned)(y0+1) < (unsigned)Wl) ? wy         : 0.f) * a;
                    const int x0c = min(max(x0, 0), Wl - 1), x1c = min(max(x0 + 1, 0), Wl - 1);
                    const int y0c = min(max(y0, 0), Wl - 1), y1c = min(max(y0 + 1, 0), Wl - 1);
                    const float w00 = ax0 * ay0, w01 = ax1 * ay0;
                    const float w10 = ax0 * ay1, w11 = ax1 * ay1;
                    const int r0 = base + (y0c * Wl + x0c) * CDIM;
                    const int r1 = base + (y0c * Wl + x1c) * CDIM;
                    const int r2 = base + (y1c * Wl + x0c) * CDIM;
                    const int r3 = base + (y1c * Wl + x1c) * CDIM;
                    f32x4 a0 = *(const f32x4*)(feat_f32 + r0);
                    f32x4 a1 = *(const f32x4*)(feat_f32 + r0 + 4);
                    f32x4 b0 = *(const f32x4*)(feat_f32 + r1);
                    f32x4 b1 = *(const f32x4*)(feat_f32 + r1 + 4);
                    f32x4 c0v = *(const f32x4*)(feat_f32 + r2);
                    f32x4 c1 = *(const f32x4*)(feat_f32 + r2 + 4);
                    f32x4 d0 = *(const f32x4*)(feat_f32 + r3);
                    f32x4 d1 = *(const f32x4*)(feat_f32 + r3 + 4);
                    #pragma unroll
                    for (int c = 0; c < 4; ++c) {
                        acc[c]     += w00*a0[c] + w01*b0[c] + w10*c0v[c] + w11*d0[c];
                        acc[c + 4] += w00*a1[c] + w01*b1[c] + w10*c1[c]  + w11*d1[c];
                    }
                }
            }
            bf16x8 pv;
            #pragma unroll
            for (int c = 0; c < 8; ++c) pv[c] = f2bf(acc[c]);
            *(bf16x8*)&pre_lds[i * QSTR + c0] = pv;
        }
    }
    __syncthreads();

    {
        f32x4 acc[4];
        #pragma unroll
        for (int j = 0; j < 4; ++j) acc[j] = (f32x4){0.f, 0.f, 0.f, 0.f};
        const short* bb = Wt_out + qr * 256 + quad * 8;
        #pragma unroll
        for (int s = 0; s < 8; ++s) {
            const bf16x8 af = *(const bf16x8*)&pre_lds[qr * QSTR + s * 32 + quad * 8];
            #pragma unroll
            for (int j = 0; j < 4; ++j) {
                const bf16x8 bf = *(const bf16x8*)(bb + ((j * 4 + wave) * 16) * 256 + s * 32);
                acc[j] = __builtin_amdgcn_mfma_f32_16x16x32_bf16(af, bf, acc[j], 0, 0, 0);
            }
        }
        #pragma unroll
        for (int j = 0; j < 4; ++j) {
            const int col = (j * 4 + wave) * 16 + qr;
            const float bo = b_out[col];
            #pragma unroll
            for (int r = 0; r < 4; ++r)
                out[(qbase + quad * 4 + r) * CDIM + col] = acc[j][r] + bo;
        }
    }
}

extern "C" void kernel_launch(void* const* d_in, const int* in_sizes, int n_in,
                              void* d_out, int out_size, void* d_ws, size_t ws_size,
                              hipStream_t stream) {
    const float* query   = (const float*)d_in[0];
    const float* ref_pts = (const float*)d_in[1];
    const float* feat    = (const float*)d_in[2];
    const float* W_off  = (const float*)d_in[5];
    const float* b_off  = (const float*)d_in[6];
    const float* W_attn = (const float*)d_in[7];
    const float* b_attn = (const float*)d_in[8];
    const float* W_out  = (const float*)d_in[9];
    const float* b_out  = (const float*)d_in[10];
    float* out = (float*)d_out;

    const int B = 2;
    const int Len = in_sizes[1] / (B * 2);
    const int rows = B * Len;                     // 43520
    const size_t feat_elems = (size_t)rows * CDIM;

    char* ws = (char*)d_ws;
    short* wt = (short*)ws;                       // 327680 B
    _Float16* feath = (_Float16*)(ws + 327680);   // feat_elems*2
    const size_t need = 327680 + feat_elems * 2;  // ~22.6 MB total — keep ws minimal

    if (ws_size >= need) {
        const int n4 = (int)(feat_elems / 4);
        const int fblocks = (n4 + 255) / 256;
        convert_all<<<640 + fblocks, 256, 0, stream>>>(W_off, W_attn, W_out, feat,
                                                       wt, feath, n4);
        msda_mega<<<rows / QB, 256, 0, stream>>>(query, ref_pts, feath, wt,
                                                 b_off, b_attn, b_out, out, Len);
    } else {
        convert_all<<<640, 256, 0, stream>>>(W_off, W_attn, W_out, feat,
                                             wt, (_Float16*)nullptr, 0);
        msda_fused_fb<<<rows / QB, 256, 0, stream>>>(query, ref_pts, feat, wt,
                                                     b_off, b_attn, b_out, out, Len);
    }
}

// Round 7
// 297.346 us; speedup vs baseline: 1.2596x; 1.2596x over previous
//
#include <hip/hip_runtime.h>

// MSDeformAttn — R7: 2-launch mega, occupancy-tuned.
//  vs R6: (1) __launch_bounds__(256,5) + LDS 34.3->24.7 KB (offs stored f16x2
//  in q-union) => residency cap 16->20 waves/CU; (2) 1-point software-pipelined
//  gather (loads for point p in flight while accumulating p-1); (3) lane-linear
//  packed qp => conflict-free MFMA A-frag ds_read_b128.
// B=2, C=256, nH=8, nL=4, nP=4, hd=32, Len=21760.
// Shapes compile-time: [[128,128],[64,64],[32,32],[16,16]], starts [0,16384,20480,21504].

#define NH 8
#define NL 4
#define NP 4
#define CDIM 256
#define HD 32
#define QB 16
#define QSTR 264   // fallback kernel only
#define ASTR 132   // fallback kernel only

typedef short bf16x8 __attribute__((ext_vector_type(8)));
typedef float f32x4  __attribute__((ext_vector_type(4)));
typedef _Float16 f16x8v __attribute__((ext_vector_type(8)));
typedef _Float16 f16x4v __attribute__((ext_vector_type(4)));
typedef _Float16 f16x2v __attribute__((ext_vector_type(2)));

#define SPLAT8(x) (f16x8v){(x),(x),(x),(x),(x),(x),(x),(x)}

__device__ __forceinline__ short f2bf(float x) {
    union { float f; unsigned u; } v; v.f = x;
    const unsigned r = v.u + 0x7FFFu + ((v.u >> 16) & 1u);
    return (short)(r >> 16);
}

__constant__ int LVL_S_C[4] = {0, 16384, 20480, 21504};

// ---- convert: weights (blocks [0,640)) + features f16 (blocks [640,...)) ----
__global__ __launch_bounds__(256) void convert_all(
    const float* __restrict__ W_off, const float* __restrict__ W_attn,
    const float* __restrict__ W_out, const float* __restrict__ feat,
    short* __restrict__ wt, _Float16* __restrict__ fh, int n4)
{
    const int bid = blockIdx.x;
    if (bid < 640) {
        const int gid = bid * 256 + threadIdx.x;
        if (gid < 65536) {
            const int c = gid >> 8, k = gid & 255;
            wt[gid] = f2bf(W_off[k * 256 + c]);
        } else if (gid < 98304) {
            const int g = gid - 65536, c = g >> 8, k = g & 255;
            wt[gid] = f2bf(W_attn[k * 128 + c]);
        } else if (gid < 163840) {
            const int g = gid - 98304, c = g >> 8, k = g & 255;
            wt[gid] = f2bf(W_out[k * 256 + c]);
        }
    } else {
        const int gid = (bid - 640) * 256 + threadIdx.x;
        if (gid < n4) {
            const float4 v = *(const float4*)&feat[gid * 4];
            f16x4v o;
            o[0] = (_Float16)v.x; o[1] = (_Float16)v.y;
            o[2] = (_Float16)v.z; o[3] = (_Float16)v.w;
            *(f16x4v*)&fh[gid * 4] = o;
        }
    }
}

// ---- mega: gemm1 (MFMA) -> softmax -> pipelined sampler -> gemm2 ----
__global__ __launch_bounds__(256, 5) void msda_mega(
    const float* __restrict__ query, const float* __restrict__ ref_pts,
    const _Float16* __restrict__ feath, const short* __restrict__ wt,
    const float* __restrict__ b_off, const float* __restrict__ b_attn,
    const float* __restrict__ b_out, float* __restrict__ out, int Len)
{
    const int t = threadIdx.x;
    const int lane = t & 63;
    const int wave = t >> 6;
    const int qr = lane & 15;
    const int quad = lane >> 4;
    const long long qbase = (long long)blockIdx.x * QB;
    const int b = (int)(qbase / Len);   // Len % QB == 0, no crossing

    // union (8192 B): qp (bf16, packed lane-linear) then offs f16 [i][pi*16+h*2+xy]
    __shared__ __align__(16) short uni[QB * CDIM];
    short* qp = uni;
    _Float16* offs16 = (_Float16*)uni;
    __shared__ float aw_lds[QB * 128];                  // 8192 B, [i][(l*4+p)*8+h]
    __shared__ __align__(16) short pre_lds[QB * CDIM];  // 8192 B, packed lane-linear
    __shared__ float ref_sm[QB][2];
    // total 24704 B -> 6 blocks/CU by LDS; VGPR cap 102 -> 5 waves/SIMD (20 waves/CU)

    // ---- stage query (fp32 -> bf16, packed: chunk = (k>>5)*64 + ((k>>3)&3)*16 + i) ----
    #pragma unroll
    for (int it = 0; it < 4; ++it) {
        const int e = it * 1024 + t * 4;
        const int i = e >> 8, k = e & 255;
        const float4 v = *(const float4*)&query[(qbase + i) * CDIM + k];
        const int chunk = (k >> 5) * 64 + ((k >> 3) & 3) * 16 + i;
        short4 o;
        o.x = f2bf(v.x); o.y = f2bf(v.y); o.z = f2bf(v.z); o.w = f2bf(v.w);
        *(short4*)&qp[chunk * 8 + (k & 7)] = o;
    }
    if (t < QB * 2) ref_sm[t >> 1][t & 1] = ref_pts[(qbase + (t >> 1)) * 2 + (t & 1)];
    __syncthreads();

    const short* __restrict__ Wt_off  = wt;
    const short* __restrict__ Wt_attn = wt + 65536;
    const short* __restrict__ Wt_out  = wt + 98304;

    // ---- GEMM1: offs (N=256) + attn logits (N=128) ----
    {
        f32x4 acc[4], acca[2];
        #pragma unroll
        for (int j = 0; j < 4; ++j) acc[j] = (f32x4){0.f, 0.f, 0.f, 0.f};
        #pragma unroll
        for (int j = 0; j < 2; ++j) acca[j] = (f32x4){0.f, 0.f, 0.f, 0.f};

        const short* bb_off  = Wt_off  + qr * 256 + quad * 8;
        const short* bb_attn = Wt_attn + qr * 256 + quad * 8;
        #pragma unroll
        for (int s = 0; s < 8; ++s) {
            const bf16x8 af = *(const bf16x8*)&qp[(s * 64 + lane) * 8];  // conflict-free
            #pragma unroll
            for (int j = 0; j < 4; ++j) {
                const bf16x8 bf = *(const bf16x8*)(bb_off + ((j * 4 + wave) * 16) * 256 + s * 32);
                acc[j] = __builtin_amdgcn_mfma_f32_16x16x32_bf16(af, bf, acc[j], 0, 0, 0);
            }
            #pragma unroll
            for (int j = 0; j < 2; ++j) {
                const bf16x8 bf = *(const bf16x8*)(bb_attn + ((j * 4 + wave) * 16) * 256 + s * 32);
                acca[j] = __builtin_amdgcn_mfma_f32_16x16x32_bf16(af, bf, acca[j], 0, 0, 0);
            }
        }
        __syncthreads();   // all qp reads done; union becomes offs16

        // D layout: col = qr, row = quad*4 + r.
        #pragma unroll
        for (int j = 0; j < 4; ++j) {
            const int col = (j * 4 + wave) * 16 + qr;
            const float bo = b_off[col];
            const int h = col >> 5, rem = col & 31;   // rem = pi*2 + xy
            const int pos = (rem >> 1) * 16 + h * 2 + (rem & 1);
            #pragma unroll
            for (int r = 0; r < 4; ++r)
                offs16[(quad * 4 + r) * 256 + pos] = (_Float16)(acc[j][r] + bo);
        }
        #pragma unroll
        for (int j = 0; j < 2; ++j) {
            const int col = (j * 4 + wave) * 16 + qr;
            const float ba = b_attn[col];
            const int h = col >> 4, rem = col & 15;   // rem = pi
            #pragma unroll
            for (int r = 0; r < 4; ++r)
                aw_lds[(quad * 4 + r) * 128 + rem * 8 + h] = acca[j][r] + ba;
        }
    }
    __syncthreads();

    // ---- softmax per (row, head), 128 threads ----
    if (t < QB * NH) {
        const int i = t >> 3, h = t & 7;
        float* row = &aw_lds[i * 128];
        float vals[16], mx = -1e30f;
        #pragma unroll
        for (int j = 0; j < 16; ++j) { vals[j] = row[j * 8 + h]; mx = fmaxf(mx, vals[j]); }
        float s = 0.f;
        #pragma unroll
        for (int j = 0; j < 16; ++j) { vals[j] = __expf(vals[j] - mx); s += vals[j]; }
        const float inv = 1.f / s;
        #pragma unroll
        for (int j = 0; j < 16; ++j) row[j * 8 + h] = vals[j] * inv;
    }
    __syncthreads();

    // ---- sampling: 2 passes x 8 rows; 32 lanes/row (h = l32>>2, ct = l32&3);
    //      1-point software pipeline: loads for pi in flight while accumulating pi-1 ----
    {
        const int rl = t >> 5;
        const int l32 = t & 31;
        const int h = l32 >> 2, ct = l32 & 3;
        const int c0 = h * HD + ct * 8;
        #pragma unroll 1
        for (int pass = 0; pass < 2; ++pass) {
            const int i = pass * 8 + rl;
            const float rx = ref_sm[i][0], ry = ref_sm[i][1];
            const _Float16* __restrict__ offr = &offs16[i * 256 + h * 2];
            const float* __restrict__ awr = &aw_lds[i * 128 + h];
            float acc[8];
            #pragma unroll
            for (int c = 0; c < 8; ++c) acc[c] = 0.f;
            f16x8v p00, p01, p10, p11;
            float q00 = 0.f, q01 = 0.f, q10 = 0.f, q11 = 0.f;
            #pragma unroll
            for (int pi = 0; pi < 16; ++pi) {
                const int l = pi >> 2;
                const int Wl = 128 >> l;
                const int base = (b * Len + LVL_S_C[l]) * CDIM + c0;
                const f16x2v oxy = *(const f16x2v*)(offr + pi * 16);
                const float a = awr[pi * 8];
                const float x = fmaf(rx, (float)Wl, (float)oxy[0]) - 0.5f;
                const float y = fmaf(ry, (float)Wl, (float)oxy[1]) - 0.5f;
                const float xf = floorf(x), yf = floorf(y);
                const int x0 = (int)xf, y0 = (int)yf;
                const float wx = x - xf, wy = y - yf;
                const float ax0 = ((unsigned)x0       < (unsigned)Wl) ? (1.f - wx) : 0.f;
                const float ax1 = ((unsigned)(x0 + 1) < (unsigned)Wl) ? wx         : 0.f;
                const float ay0 = (((unsigned)y0       < (unsigned)Wl) ? (1.f - wy) : 0.f) * a;
                const float ay1 = (((unsigned)(y0 + 1) < (unsigned)Wl) ? wy         : 0.f) * a;
                const int x0c = min(max(x0, 0), Wl - 1), x1c = min(max(x0 + 1, 0), Wl - 1);
                const int y0c = min(max(y0, 0), Wl - 1), y1c = min(max(y0 + 1, 0), Wl - 1);
                const int r00 = base + (y0c * Wl + x0c) * CDIM;
                const int r01 = base + (y0c * Wl + x1c) * CDIM;
                const int r10 = base + (y1c * Wl + x0c) * CDIM;
                const int r11 = base + (y1c * Wl + x1c) * CDIM;
                const f16x8v n00 = *(const f16x8v*)(feath + r00);
                const f16x8v n01 = *(const f16x8v*)(feath + r01);
                const f16x8v n10 = *(const f16x8v*)(feath + r10);
                const f16x8v n11 = *(const f16x8v*)(feath + r11);
                if (pi > 0) {
                    f16x8v bil = p00 * SPLAT8((_Float16)q00);
                    bil += p01 * SPLAT8((_Float16)q01);
                    bil += p10 * SPLAT8((_Float16)q10);
                    bil += p11 * SPLAT8((_Float16)q11);
                    #pragma unroll
                    for (int c = 0; c < 8; ++c) acc[c] += (float)bil[c];
                }
                p00 = n00; p01 = n01; p10 = n10; p11 = n11;
                q00 = ax0 * ay0; q01 = ax1 * ay0; q10 = ax0 * ay1; q11 = ax1 * ay1;
            }
            {   // drain last point
                f16x8v bil = p00 * SPLAT8((_Float16)q00);
                bil += p01 * SPLAT8((_Float16)q01);
                bil += p10 * SPLAT8((_Float16)q10);
                bil += p11 * SPLAT8((_Float16)q11);
                #pragma unroll
                for (int c = 0; c < 8; ++c) acc[c] += (float)bil[c];
            }
            bf16x8 pv;
            #pragma unroll
            for (int c = 0; c < 8; ++c) pv[c] = f2bf(acc[c]);
            // packed lane-linear: chunk = h*64 + ct*16 + i  (s=h, quad=ct, row=i)
            *(bf16x8*)&pre_lds[(h * 64 + ct * 16 + i) * 8] = pv;
        }
    }
    __syncthreads();

    // ---- GEMM2: out = pre @ W_out + b_out ----
    {
        f32x4 acc[4];
        #pragma unroll
        for (int j = 0; j < 4; ++j) acc[j] = (f32x4){0.f, 0.f, 0.f, 0.f};
        const short* bb = Wt_out + qr * 256 + quad * 8;
        #pragma unroll
        for (int s = 0; s < 8; ++s) {
            const bf16x8 af = *(const bf16x8*)&pre_lds[(s * 64 + lane) * 8];  // conflict-free
            #pragma unroll
            for (int j = 0; j < 4; ++j) {
                const bf16x8 bf = *(const bf16x8*)(bb + ((j * 4 + wave) * 16) * 256 + s * 32);
                acc[j] = __builtin_amdgcn_mfma_f32_16x16x32_bf16(af, bf, acc[j], 0, 0, 0);
            }
        }
        #pragma unroll
        for (int j = 0; j < 4; ++j) {
            const int col = (j * 4 + wave) * 16 + qr;
            const float bo = b_out[col];
            #pragma unroll
            for (int r = 0; r < 4; ++r)
                out[(qbase + quad * 4 + r) * CDIM + col] = acc[j][r] + bo;
        }
    }
}

// ---- fallback: fused kernel, fp32 features (ws too small) ----
__global__ __launch_bounds__(256) void msda_fused_fb(
    const float* __restrict__ query, const float* __restrict__ ref_pts,
    const float* __restrict__ feat_f32, const short* __restrict__ wt,
    const float* __restrict__ b_off, const float* __restrict__ b_attn,
    const float* __restrict__ b_out, float* __restrict__ out, int Len)
{
    const int t = threadIdx.x;
    const int lane = t & 63;
    const int wave = t >> 6;
    const int qr = lane & 15;
    const int quad = lane >> 4;
    const long long qbase = (long long)blockIdx.x * QB;
    const int b = (int)(qbase / Len);

    __shared__ __align__(16) char uni[QB * QSTR * 4];
    short* qp = (short*)uni;
    float* offs_lds = (float*)uni;
    __shared__ float aw_lds[QB * ASTR];
    __shared__ __align__(16) short pre_lds[QB * QSTR];
    __shared__ float ref_sm[QB][2];

    #pragma unroll
    for (int it = 0; it < 4; ++it) {
        const int e = it * 1024 + t * 4;
        const int i = e >> 8, k = e & 255;
        const float4 v = *(const float4*)&query[(qbase + i) * CDIM + k];
        short4 o;
        o.x = f2bf(v.x); o.y = f2bf(v.y); o.z = f2bf(v.z); o.w = f2bf(v.w);
        *(short4*)&qp[i * QSTR + k] = o;
    }
    if (t < QB * 2) ref_sm[t >> 1][t & 1] = ref_pts[(qbase + (t >> 1)) * 2 + (t & 1)];
    __syncthreads();

    const short* __restrict__ Wt_off  = wt;
    const short* __restrict__ Wt_attn = wt + 65536;
    const short* __restrict__ Wt_out  = wt + 98304;

    {
        f32x4 acc[4], acca[2];
        #pragma unroll
        for (int j = 0; j < 4; ++j) acc[j] = (f32x4){0.f, 0.f, 0.f, 0.f};
        #pragma unroll
        for (int j = 0; j < 2; ++j) acca[j] = (f32x4){0.f, 0.f, 0.f, 0.f};
        const short* bb_off  = Wt_off  + qr * 256 + quad * 8;
        const short* bb_attn = Wt_attn + qr * 256 + quad * 8;
        #pragma unroll
        for (int s = 0; s < 8; ++s) {
            const bf16x8 af = *(const bf16x8*)&qp[qr * QSTR + s * 32 + quad * 8];
            #pragma unroll
            for (int j = 0; j < 4; ++j) {
                const bf16x8 bf = *(const bf16x8*)(bb_off + ((j * 4 + wave) * 16) * 256 + s * 32);
                acc[j] = __builtin_amdgcn_mfma_f32_16x16x32_bf16(af, bf, acc[j], 0, 0, 0);
            }
            #pragma unroll
            for (int j = 0; j < 2; ++j) {
                const bf16x8 bf = *(const bf16x8*)(bb_attn + ((j * 4 + wave) * 16) * 256 + s * 32);
                acca[j] = __builtin_amdgcn_mfma_f32_16x16x32_bf16(af, bf, acca[j], 0, 0, 0);
            }
        }
        __syncthreads();
        #pragma unroll
        for (int j = 0; j < 4; ++j) {
            const int col = (j * 4 + wave) * 16 + qr;
            const float bo = b_off[col];
            const int h = col >> 5, rem = col & 31;
            #pragma unroll
            for (int r = 0; r < 4; ++r)
                offs_lds[(quad * 4 + r) * QSTR + rem * 8 + h] = acc[j][r] + bo;
        }
        #pragma unroll
        for (int j = 0; j < 2; ++j) {
            const int col = (j * 4 + wave) * 16 + qr;
            const float ba = b_attn[col];
            const int h = col >> 4, rem = col & 15;
            #pragma unroll
            for (int r = 0; r < 4; ++r)
                aw_lds[(quad * 4 + r) * ASTR + rem * 8 + h] = acca[j][r] + ba;
        }
    }
    __syncthreads();

    if (t < QB * NH) {
        const int i = t >> 3, h = t & 7;
        float* row = &aw_lds[i * ASTR];
        float vals[16], mx = -1e30f;
        #pragma unroll
        for (int j = 0; j < 16; ++j) { vals[j] = row[j * 8 + h]; mx = fmaxf(mx, vals[j]); }
        float s = 0.f;
        #pragma unroll
        for (int j = 0; j < 16; ++j) { vals[j] = __expf(vals[j] - mx); s += vals[j]; }
        const float inv = 1.f / s;
        #pragma unroll
        for (int j = 0; j < 16; ++j) row[j * 8 + h] = vals[j] * inv;
    }
    __syncthreads();

    {
        const int rl = t >> 5;
        const int l32 = t & 31;
        const int h = l32 >> 2, ct = l32 & 3;
        const int c0 = h * HD + ct * 8;
        #pragma unroll 1
        for (int pass = 0; pass < 2; ++pass) {
            const int i = pass * 8 + rl;
            const float rx = ref_sm[i][0], ry = ref_sm[i][1];
            const float* __restrict__ offr = &offs_lds[i * QSTR];
            const float* __restrict__ awr  = &aw_lds[i * ASTR];
            float acc[8];
            #pragma unroll
            for (int c = 0; c < 8; ++c) acc[c] = 0.f;
            #pragma unroll
            for (int l = 0; l < NL; ++l) {
                const int Wl = 128 >> l;
                const int base = (b * Len + LVL_S_C[l]) * CDIM + c0;
                #pragma unroll 2
                for (int p = 0; p < NP; ++p) {
                    const int pi = l * 4 + p;
                    const float ox = offr[pi * 16 + h];
                    const float oy = offr[pi * 16 + 8 + h];
                    const float a  = awr[pi * 8 + h];
                    const float x = fmaf(rx, (float)Wl, ox) - 0.5f;
                    const float y = fmaf(ry, (float)Wl, oy) - 0.5f;
                    const float xf = floorf(x), yf = floorf(y);
                    const int x0 = (int)xf, y0 = (int)yf;
                    const float wx = x - xf, wy = y - yf;
                    const float ax0 = ((unsigned)x0       < (unsigned)Wl) ? (1.f - wx) : 0.f;
                    const float ax1 = ((unsigned)(x0 + 1) < (unsigned)Wl) ? wx         : 0.f;
                    const float ay0 = (((unsigned)y0       < (unsigned)Wl) ? (1.f - wy) : 0.f) * a;
                    const float ay1 = (((unsigned)(y0 + 1) < (unsigned)Wl) ? wy         : 0.f) * a;
                    const int x0c = min(max(x0, 0), Wl - 1), x1c = min(max(x0 + 1, 0), Wl - 1);
                    const int y0c = min(max(y0, 0), Wl - 1), y1c = min(max(y0 + 1, 0), Wl - 1);
                    const float w00 = ax0 * ay0, w01 = ax1 * ay0;
                    const float w10 = ax0 * ay1, w11 = ax1 * ay1;
                    const int r0 = base + (y0c * Wl + x0c) * CDIM;
                    const int r1 = base + (y0c * Wl + x1c) * CDIM;
                    const int r2 = base + (y1c * Wl + x0c) * CDIM;
                    const int r3 = base + (y1c * Wl + x1c) * CDIM;
                    f32x4 a0 = *(const f32x4*)(feat_f32 + r0);
                    f32x4 a1 = *(const f32x4*)(feat_f32 + r0 + 4);
                    f32x4 b0 = *(const f32x4*)(feat_f32 + r1);
                    f32x4 b1 = *(const f32x4*)(feat_f32 + r1 + 4);
                    f32x4 c0v = *(const f32x4*)(feat_f32 + r2);
                    f32x4 c1 = *(const f32x4*)(feat_f32 + r2 + 4);
                    f32x4 d0 = *(const f32x4*)(feat_f32 + r3);
                    f32x4 d1 = *(const f32x4*)(feat_f32 + r3 + 4);
                    #pragma unroll
                    for (int c = 0; c < 4; ++c) {
                        acc[c]     += w00*a0[c] + w01*b0[c] + w10*c0v[c] + w11*d0[c];
                        acc[c + 4] += w00*a1[c] + w01*b1[c] + w10*c1[c]  + w11*d1[c];
                    }
                }
            }
            bf16x8 pv;
            #pragma unroll
            for (int c = 0; c < 8; ++c) pv[c] = f2bf(acc[c]);
            *(bf16x8*)&pre_lds[i * QSTR + c0] = pv;
        }
    }
    __syncthreads();

    {
        f32x4 acc[4];
        #pragma unroll
        for (int j = 0; j < 4; ++j) acc[j] = (f32x4){0.f, 0.f, 0.f, 0.f};
        const short* bb = Wt_out + qr * 256 + quad * 8;
        #pragma unroll
        for (int s = 0; s < 8; ++s) {
            const bf16x8 af = *(const bf16x8*)&pre_lds[qr * QSTR + s * 32 + quad * 8];
            #pragma unroll
            for (int j = 0; j < 4; ++j) {
                const bf16x8 bf = *(const bf16x8*)(bb + ((j * 4 + wave) * 16) * 256 + s * 32);
                acc[j] = __builtin_amdgcn_mfma_f32_16x16x32_bf16(af, bf, acc[j], 0, 0, 0);
            }
        }
        #pragma unroll
        for (int j = 0; j < 4; ++j) {
            const int col = (j * 4 + wave) * 16 + qr;
            const float bo = b_out[col];
            #pragma unroll
            for (int r = 0; r < 4; ++r)
                out[(qbase + quad * 4 + r) * CDIM + col] = acc[j][r] + bo;
        }
    }
}

extern "C" void kernel_launch(void* const* d_in, const int* in_sizes, int n_in,
                              void* d_out, int out_size, void* d_ws, size_t ws_size,
                              hipStream_t stream) {
    const float* query   = (const float*)d_in[0];
    const float* ref_pts = (const float*)d_in[1];
    const float* feat    = (const float*)d_in[2];
    const float* W_off  = (const float*)d_in[5];
    const float* b_off  = (const float*)d_in[6];
    const float* W_attn = (const float*)d_in[7];
    const float* b_attn = (const float*)d_in[8];
    const float* W_out  = (const float*)d_in[9];
    const float* b_out  = (const float*)d_in[10];
    float* out = (float*)d_out;

    const int B = 2;
    const int Len = in_sizes[1] / (B * 2);
    const int rows = B * Len;                     // 43520
    const size_t feat_elems = (size_t)rows * CDIM;

    char* ws = (char*)d_ws;
    short* wt = (short*)ws;                       // 327680 B
    _Float16* feath = (_Float16*)(ws + 327680);   // feat_elems*2
    const size_t need = 327680 + feat_elems * 2;  // ~22.6 MB — keep ws minimal

    if (ws_size >= need) {
        const int n4 = (int)(feat_elems / 4);
        const int fblocks = (n4 + 255) / 256;
        convert_all<<<640 + fblocks, 256, 0, stream>>>(W_off, W_attn, W_out, feat,
                                                       wt, feath, n4);
        msda_mega<<<rows / QB, 256, 0, stream>>>(query, ref_pts, feath, wt,
                                                 b_off, b_attn, b_out, out, Len);
    } else {
        convert_all<<<640, 256, 0, stream>>>(W_off, W_attn, W_out, feat,
                                             wt, (_Float16*)nullptr, 0);
        msda_fused_fb<<<rows / QB, 256, 0, stream>>>(query, ref_pts, feat, wt,
                                                     b_off, b_attn, b_out, out, Len);
    }
}